// Round 2
// baseline (285.904 us; speedup 1.0000x reference)
//
#include <hip/hip_runtime.h>
#include <hip/hip_bf16.h>
#include <math.h>

// ---------------------------------------------------------------------------
// MAB block: Qp=Q@Wq.T+bq, Kp=K@Wk.T+bk, Vp=K@Wv.T+bv (8 heads, dh=32)
// attn = softmax(Qp Kp^T / sqrt(32)) @ Vp ; out = attn@Wo.T+bo ; LN0 ;
// out = LN1(out + relu(out)).  All GEMMs bf16 MFMA 16x16x32, fp32 accum.
// ---------------------------------------------------------------------------

typedef __attribute__((ext_vector_type(4))) float f32x4;
typedef __attribute__((ext_vector_type(8))) short s16x8;

#define MFMA_BF16(A, B, C) __builtin_amdgcn_mfma_f32_16x16x32_bf16((A), (B), (C), 0, 0, 0)

static __device__ __forceinline__ unsigned short f2bf(float f) {
    union { float f; unsigned u; } v; v.f = f;
    unsigned u = v.u;
    unsigned r = (u + 0x7FFFu + ((u >> 16) & 1u)) >> 16;  // RNE
    return (unsigned short)r;
}

// ---- fp32 -> bf16 bulk convert (vectorized, 4 elems/thread) ----
__global__ __launch_bounds__(256) void k_cvt(const float* __restrict__ src,
                                             unsigned short* __restrict__ dst, int n4) {
    int idx = blockIdx.x * 256 + threadIdx.x;
    if (idx >= n4) return;
    float4 v = ((const float4*)src)[idx];
    ushort4 o;
    o.x = f2bf(v.x); o.y = f2bf(v.y); o.z = f2bf(v.z); o.w = f2bf(v.w);
    ((ushort4*)dst)[idx] = o;
}

// ---- row-major head-split projection: Y[b,h,n,dh] = (X @ W^T + bias)*scale ----
// X [8192,256] bf16, W [256,256] bf16 row-major (out = X@W.T), Y [B,H,4096,32] bf16
__global__ __launch_bounds__(256) void k_proj_rm(const unsigned short* __restrict__ X,
                                                 const unsigned short* __restrict__ W,
                                                 const float* __restrict__ bias,
                                                 unsigned short* __restrict__ Y,
                                                 float scale) {
    const int wv = threadIdx.x >> 6, lid = threadIdx.x & 63;
    const int i = lid & 15, G = lid >> 4;
    const int m0 = blockIdx.x * 64 + wv * 16;
    f32x4 acc[16];
#pragma unroll
    for (int nf = 0; nf < 16; ++nf) acc[nf] = f32x4{0.f, 0.f, 0.f, 0.f};
    const unsigned short* Xrow = X + (size_t)(m0 + i) * 256;
#pragma unroll
    for (int k0 = 0; k0 < 256; k0 += 32) {
        s16x8 a = *(const s16x8*)(Xrow + k0 + G * 8);
#pragma unroll
        for (int nf = 0; nf < 16; ++nf) {
            s16x8 b = *(const s16x8*)(W + (size_t)(nf * 16 + i) * 256 + k0 + G * 8);
            acc[nf] = MFMA_BF16(a, b, acc[nf]);
        }
    }
#pragma unroll
    for (int nf = 0; nf < 16; ++nf) {
        int col = nf * 16 + i;
        float bv = bias[col];
        int h = col >> 5, dh = col & 31;
#pragma unroll
        for (int r = 0; r < 4; ++r) {
            int m = m0 + G * 4 + r;
            int bb = m >> 12, n = m & 4095;
            float v = (acc[nf][r] + bv) * scale;
            Y[(size_t)(((bb << 3) + h) * 4096 + n) * 32 + dh] = f2bf(v);
        }
    }
}

// ---- transposed projection: Vt[b,h,dh,n] = (K @ Wv^T + bv)^T  (= Wv @ K^T) ----
// grid (128 n-tiles, 4 dv-tiles)
__global__ __launch_bounds__(256) void k_proj_tr(const unsigned short* __restrict__ Kb,
                                                 const unsigned short* __restrict__ W,
                                                 const float* __restrict__ bias,
                                                 unsigned short* __restrict__ Vt) {
    const int wv = threadIdx.x >> 6, lid = threadIdx.x & 63;
    const int i = lid & 15, G = lid >> 4;
    const int n0 = blockIdx.x * 64;
    const int dv0 = blockIdx.y * 64 + wv * 16;
    f32x4 acc[4];
#pragma unroll
    for (int nf = 0; nf < 4; ++nf) acc[nf] = f32x4{0.f, 0.f, 0.f, 0.f};
    const unsigned short* Wrow = W + (size_t)(dv0 + i) * 256;
#pragma unroll
    for (int k0 = 0; k0 < 256; k0 += 32) {
        s16x8 a = *(const s16x8*)(Wrow + k0 + G * 8);
#pragma unroll
        for (int nf = 0; nf < 4; ++nf) {
            s16x8 b = *(const s16x8*)(Kb + (size_t)(n0 + nf * 16 + i) * 256 + k0 + G * 8);
            acc[nf] = MFMA_BF16(a, b, acc[nf]);
        }
    }
#pragma unroll
    for (int r = 0; r < 4; ++r) {
        int dv = dv0 + G * 4 + r;
        float bv = bias[dv];
        int h = dv >> 5, dh = dv & 31;
#pragma unroll
        for (int nf = 0; nf < 4; ++nf) {
            int n = n0 + nf * 16 + i;
            int bb = n >> 12, nn = n & 4095;
            Vt[(size_t)(((bb << 3) + h) * 32 + dh) * 4096 + nn] = f2bf(acc[nf][r] + bv);
        }
    }
}

// ---- flash attention: per block one (b,h,q-tile of 64); 4 waves x 16 q-rows ----
// Qp/Kp [16][4096][32] bf16 (Qp pre-scaled by log2(e)/sqrt(32)), Vt [16][32][4096]
// Oa [8192][256] bf16 (softmax-normalized attention output, heads concatenated)
__global__ __launch_bounds__(256) void k_attn(const unsigned short* __restrict__ Qp,
                                              const unsigned short* __restrict__ Kp,
                                              const unsigned short* __restrict__ Vt,
                                              unsigned short* __restrict__ Oa) {
    __shared__ unsigned short plds[4 * 16 * 64];  // per-wave 16x64 bf16 P tile (swizzled)
    const int wv = threadIdx.x >> 6, lid = threadIdx.x & 63;
    const int i = lid & 15, G = lid >> 4;
    const int swz = i & 7;
    const f32x4 ZERO4 = {0.f, 0.f, 0.f, 0.f};
    int bid = blockIdx.x;
    int wg = ((bid & 7) << 7) | (bid >> 3);  // XCD swizzle (1024 % 8 == 0, bijective)
    int bh = wg >> 6, qt = wg & 63;
    const unsigned short* Qh = Qp + (size_t)bh * 4096 * 32;
    const unsigned short* Kh = Kp + (size_t)bh * 4096 * 32;
    const unsigned short* Vh = Vt + (size_t)bh * 32 * 4096;
    const int q0 = qt * 64 + wv * 16;
    s16x8 qf = *(const s16x8*)(Qh + (size_t)(q0 + i) * 32 + G * 8);  // B-frag: Q[i][k]
    f32x4 accO[2];
    accO[0] = ZERO4;
    accO[1] = ZERO4;
    float mrun = -1e30f, lrun = 0.f;
    char* pw = (char*)(plds + wv * 16 * 64);

    for (int t = 0; t < 64; ++t) {
        const int j0 = t * 64;
        // S^T = mfma(K, Q): lane holds S[q=i][j = g*16 + G*4 + r]
        f32x4 st[4];
#pragma unroll
        for (int g = 0; g < 4; ++g) {
            s16x8 kf = *(const s16x8*)(Kh + (size_t)(j0 + g * 16 + i) * 32 + G * 8);
            st[g] = MFMA_BF16(kf, qf, ZERO4);
        }
        // row max (reduce across the 4 lane-groups holding the same q-row)
        float pmax = -1e30f;
#pragma unroll
        for (int g = 0; g < 4; ++g)
#pragma unroll
            for (int r = 0; r < 4; ++r) pmax = fmaxf(pmax, st[g][r]);
        pmax = fmaxf(pmax, __shfl_xor(pmax, 16));
        pmax = fmaxf(pmax, __shfl_xor(pmax, 32));
        // defer-max: only rescale when max grew by more than 8 (log2 domain)
        if (!__all(pmax <= mrun + 8.f)) {
            float mnew = fmaxf(mrun, pmax);
            float corr = exp2f(mrun - mnew);
            mrun = mnew;
            lrun *= corr;
            // O rows are (G*4+r); stats live in lane (G*4+r) (group 0)
            float c0 = __shfl(corr, G * 4 + 0);
            float c1 = __shfl(corr, G * 4 + 1);
            float c2 = __shfl(corr, G * 4 + 2);
            float c3 = __shfl(corr, G * 4 + 3);
#pragma unroll
            for (int nf = 0; nf < 2; ++nf) {
                accO[nf][0] *= c0; accO[nf][1] *= c1;
                accO[nf][2] *= c2; accO[nf][3] *= c3;
            }
        }
        float rsum = 0.f;
#pragma unroll
        for (int g = 0; g < 4; ++g)
#pragma unroll
            for (int r = 0; r < 4; ++r) {
                float p = exp2f(st[g][r] - mrun);
                st[g][r] = p;
                rsum += p;
            }
        rsum += __shfl_xor(rsum, 16);
        rsum += __shfl_xor(rsum, 32);
        lrun += rsum;
        // write P (bf16) to per-wave LDS tile, XOR slot-swizzled (banks spread)
#pragma unroll
        for (int g = 0; g < 4; ++g) {
#pragma unroll
            for (int hp = 0; hp < 2; ++hp) {
                unsigned pr = (unsigned)f2bf(st[g][hp * 2]) |
                              ((unsigned)f2bf(st[g][hp * 2 + 1]) << 16);
                int colb = (g * 16 + G * 4 + hp * 2) * 2;
                int slot = colb >> 4, off = colb & 15;
                *(unsigned*)(pw + i * 128 + (((slot ^ swz)) << 4) + off) = pr;
            }
        }
        // read P as A-frags (P[i][j-chunk]) and do PV
#pragma unroll
        for (int c = 0; c < 2; ++c) {
            s16x8 pf = *(const s16x8*)(pw + i * 128 + ((((c * 4 + G)) ^ swz) << 4));
#pragma unroll
            for (int nf = 0; nf < 2; ++nf) {
                s16x8 vf = *(const s16x8*)(Vh + (size_t)(nf * 16 + i) * 4096 + j0 + c * 32 + G * 8);
                accO[nf] = MFMA_BF16(pf, vf, accO[nf]);
            }
        }
    }
    // normalize and store
    float li = 1.f / lrun;
    float li0 = __shfl(li, G * 4 + 0);
    float li1 = __shfl(li, G * 4 + 1);
    float li2 = __shfl(li, G * 4 + 2);
    float li3 = __shfl(li, G * 4 + 3);
    const int bb = bh >> 3, h = bh & 7;
#pragma unroll
    for (int nf = 0; nf < 2; ++nf) {
        int col = h * 32 + nf * 16 + i;
        size_t mbase = (size_t)((bb << 12) + q0 + G * 4);
        Oa[(mbase + 0) * 256 + col] = f2bf(accO[nf][0] * li0);
        Oa[(mbase + 1) * 256 + col] = f2bf(accO[nf][1] * li1);
        Oa[(mbase + 2) * 256 + col] = f2bf(accO[nf][2] * li2);
        Oa[(mbase + 3) * 256 + col] = f2bf(accO[nf][3] * li3);
    }
}

// ---- epilogue: out = LN1( LN0(Oa@Wo^T + bo) + relu(LN0(...)) ), fp32 out ----
__global__ __launch_bounds__(256) void k_epi(const unsigned short* __restrict__ Oa,
                                             const unsigned short* __restrict__ W,
                                             const float* __restrict__ bo,
                                             const float* __restrict__ g0,
                                             const float* __restrict__ be0,
                                             const float* __restrict__ g1,
                                             const float* __restrict__ be1,
                                             float* __restrict__ out) {
    const int wv = threadIdx.x >> 6, lid = threadIdx.x & 63;
    const int i = lid & 15, G = lid >> 4;
    const int m0 = blockIdx.x * 64 + wv * 16;
    f32x4 acc[16];
#pragma unroll
    for (int nf = 0; nf < 16; ++nf) acc[nf] = f32x4{0.f, 0.f, 0.f, 0.f};
    const unsigned short* Arow = Oa + (size_t)(m0 + i) * 256;
#pragma unroll
    for (int k0 = 0; k0 < 256; k0 += 32) {
        s16x8 a = *(const s16x8*)(Arow + k0 + G * 8);
#pragma unroll
        for (int nf = 0; nf < 16; ++nf) {
            s16x8 b = *(const s16x8*)(W + (size_t)(nf * 16 + i) * 256 + k0 + G * 8);
            acc[nf] = MFMA_BF16(a, b, acc[nf]);
        }
    }
    // bias + LN0 stats (row = m0 + G*4 + r, spread over 16 lanes x 16 nf)
    f32x4 s1 = f32x4{0.f, 0.f, 0.f, 0.f}, s2 = f32x4{0.f, 0.f, 0.f, 0.f};
#pragma unroll
    for (int nf = 0; nf < 16; ++nf) {
        float bb = bo[nf * 16 + i];
#pragma unroll
        for (int r = 0; r < 4; ++r) {
            float x = acc[nf][r] + bb;
            acc[nf][r] = x;
            s1[r] += x;
            s2[r] += x * x;
        }
    }
#pragma unroll
    for (int mk = 1; mk < 16; mk <<= 1) {
#pragma unroll
        for (int r = 0; r < 4; ++r) {
            s1[r] += __shfl_xor(s1[r], mk);
            s2[r] += __shfl_xor(s2[r], mk);
        }
    }
    f32x4 mu, rs;
#pragma unroll
    for (int r = 0; r < 4; ++r) {
        mu[r] = s1[r] * (1.f / 256.f);
        float var = s2[r] * (1.f / 256.f) - mu[r] * mu[r];
        rs[r] = rsqrtf(var + 1e-5f);
    }
    // y = LN0(x); z = y + relu(y); LN1 stats
    f32x4 t1 = f32x4{0.f, 0.f, 0.f, 0.f}, t2 = f32x4{0.f, 0.f, 0.f, 0.f};
#pragma unroll
    for (int nf = 0; nf < 16; ++nf) {
        float gv = g0[nf * 16 + i], bv = be0[nf * 16 + i];
#pragma unroll
        for (int r = 0; r < 4; ++r) {
            float y = (acc[nf][r] - mu[r]) * rs[r] * gv + bv;
            float z = y + fmaxf(y, 0.f);
            acc[nf][r] = z;
            t1[r] += z;
            t2[r] += z * z;
        }
    }
#pragma unroll
    for (int mk = 1; mk < 16; mk <<= 1) {
#pragma unroll
        for (int r = 0; r < 4; ++r) {
            t1[r] += __shfl_xor(t1[r], mk);
            t2[r] += __shfl_xor(t2[r], mk);
        }
    }
    f32x4 mu2, rs2;
#pragma unroll
    for (int r = 0; r < 4; ++r) {
        mu2[r] = t1[r] * (1.f / 256.f);
        float var = t2[r] * (1.f / 256.f) - mu2[r] * mu2[r];
        rs2[r] = rsqrtf(var + 1e-5f);
    }
#pragma unroll
    for (int nf = 0; nf < 16; ++nf) {
        int col = nf * 16 + i;
        float gv = g1[col], bv = be1[col];
#pragma unroll
        for (int r = 0; r < 4; ++r) {
            out[(size_t)(m0 + G * 4 + r) * 256 + col] = (acc[nf][r] - mu2[r]) * rs2[r] * gv + bv;
        }
    }
}

extern "C" void kernel_launch(void* const* d_in, const int* in_sizes, int n_in,
                              void* d_out, int out_size, void* d_ws, size_t ws_size,
                              hipStream_t stream) {
    const float* Q   = (const float*)d_in[0];
    const float* K   = (const float*)d_in[1];
    const float* Wq  = (const float*)d_in[2];
    const float* bq  = (const float*)d_in[3];
    const float* Wk  = (const float*)d_in[4];
    const float* bk  = (const float*)d_in[5];
    const float* Wv  = (const float*)d_in[6];
    const float* bv  = (const float*)d_in[7];
    const float* Wo  = (const float*)d_in[8];
    const float* bo  = (const float*)d_in[9];
    const float* g0  = (const float*)d_in[10];
    const float* be0 = (const float*)d_in[11];
    const float* g1  = (const float*)d_in[12];
    const float* be1 = (const float*)d_in[13];
    float* out = (float*)d_out;

    char* ws = (char*)d_ws;
    unsigned short* Wqb = (unsigned short*)(ws + (size_t)0);
    unsigned short* Wkb = (unsigned short*)(ws + ((size_t)128 << 10));
    unsigned short* Wvb = (unsigned short*)(ws + ((size_t)256 << 10));
    unsigned short* Wob = (unsigned short*)(ws + ((size_t)384 << 10));
    size_t off = (size_t)512 << 10;
    const size_t big = (size_t)8192 * 256 * 2;  // 4 MB each
    unsigned short* Qb = (unsigned short*)(ws + off); off += big;
    unsigned short* Kb = (unsigned short*)(ws + off); off += big;
    unsigned short* Qp = (unsigned short*)(ws + off); off += big;
    unsigned short* Kp = (unsigned short*)(ws + off); off += big;
    unsigned short* Vt = (unsigned short*)(ws + off); off += big;
    unsigned short* Oa = (unsigned short*)(ws + off); off += big;

    // fp32 -> bf16 conversions
    k_cvt<<<2048, 256, 0, stream>>>(Q, Qb, 524288);
    k_cvt<<<2048, 256, 0, stream>>>(K, Kb, 524288);
    k_cvt<<<64, 256, 0, stream>>>(Wq, Wqb, 16384);
    k_cvt<<<64, 256, 0, stream>>>(Wk, Wkb, 16384);
    k_cvt<<<64, 256, 0, stream>>>(Wv, Wvb, 16384);
    k_cvt<<<64, 256, 0, stream>>>(Wo, Wob, 16384);

    // projections (softmax scale * log2(e) folded into Qp)
    const float qscale = 1.4426950408889634f / sqrtf(32.0f);
    k_proj_rm<<<128, 256, 0, stream>>>(Qb, Wqb, bq, Qp, qscale);
    k_proj_rm<<<128, 256, 0, stream>>>(Kb, Wkb, bk, Kp, 1.0f);
    k_proj_tr<<<dim3(128, 4), 256, 0, stream>>>(Kb, Wvb, bv, Vt);

    // flash attention
    k_attn<<<1024, 256, 0, stream>>>(Qp, Kp, Vt, Oa);

    // output projection + LN0 + residual-relu + LN1
    k_epi<<<128, 256, 0, stream>>>(Oa, Wob, bo, g0, be0, g1, be1, out);
}

// Round 3
// 200.409 us; speedup vs baseline: 1.4266x; 1.4266x over previous
//
#include <hip/hip_runtime.h>
#include <hip/hip_bf16.h>
#include <math.h>

// ---------------------------------------------------------------------------
// MAB block: Qp=Q@Wq.T+bq, Kp=K@Wk.T+bk, Vp=K@Wv.T+bv (8 heads, dh=32)
// attn = softmax(Qp Kp^T / sqrt(32)) @ Vp ; out = attn@Wo.T+bo ; LN0 ;
// out = LN1(out + relu(out)).
// Attention: 32x32x16 MFMA, swapped QK^T (lane-local softmax), in-register
// P->A-frag via v_cvt_pk_bf16_f32 + permlane32_swap (no LDS in main loop).
// ---------------------------------------------------------------------------

typedef __attribute__((ext_vector_type(4))) float f32x4;
typedef __attribute__((ext_vector_type(16))) float f32x16;
typedef __attribute__((ext_vector_type(8))) short s16x8;
typedef __attribute__((ext_vector_type(2))) unsigned u32x2;

#define MFMA_BF16(A, B, C) __builtin_amdgcn_mfma_f32_16x16x32_bf16((A), (B), (C), 0, 0, 0)
#define MFMA32(A, B, C) __builtin_amdgcn_mfma_f32_32x32x16_bf16((A), (B), (C), 0, 0, 0)

static __device__ __forceinline__ unsigned short f2bf(float f) {
    union { float f; unsigned u; } v; v.f = f;
    unsigned u = v.u;
    unsigned r = (u + 0x7FFFu + ((u >> 16) & 1u)) >> 16;  // RNE
    return (unsigned short)r;
}

static __device__ __forceinline__ unsigned cvtpk(float lo, float hi) {
    unsigned r;
    asm("v_cvt_pk_bf16_f32 %0, %1, %2" : "=v"(r) : "v"(lo), "v"(hi));
    return r;
}

static __device__ __forceinline__ s16x8 mk8(unsigned a, unsigned b, unsigned c, unsigned d) {
    union { unsigned u[4]; s16x8 v; } x;
    x.u[0] = a; x.u[1] = b; x.u[2] = c; x.u[3] = d;
    return x.v;
}

// ---- fp32 -> bf16 bulk convert (vectorized, 4 elems/thread) ----
__global__ __launch_bounds__(256) void k_cvt(const float* __restrict__ src,
                                             unsigned short* __restrict__ dst, int n4) {
    int idx = blockIdx.x * 256 + threadIdx.x;
    if (idx >= n4) return;
    float4 v = ((const float4*)src)[idx];
    ushort4 o;
    o.x = f2bf(v.x); o.y = f2bf(v.y); o.z = f2bf(v.z); o.w = f2bf(v.w);
    ((ushort4*)dst)[idx] = o;
}

// ---- row-major head-split projection: Y[b,h,n,dh] = (X @ W^T + bias)*scale ----
__global__ __launch_bounds__(256) void k_proj_rm(const unsigned short* __restrict__ X,
                                                 const unsigned short* __restrict__ W,
                                                 const float* __restrict__ bias,
                                                 unsigned short* __restrict__ Y,
                                                 float scale) {
    const int wv = threadIdx.x >> 6, lid = threadIdx.x & 63;
    const int i = lid & 15, G = lid >> 4;
    const int m0 = blockIdx.x * 64 + wv * 16;
    f32x4 acc[16];
#pragma unroll
    for (int nf = 0; nf < 16; ++nf) acc[nf] = f32x4{0.f, 0.f, 0.f, 0.f};
    const unsigned short* Xrow = X + (size_t)(m0 + i) * 256;
#pragma unroll
    for (int k0 = 0; k0 < 256; k0 += 32) {
        s16x8 a = *(const s16x8*)(Xrow + k0 + G * 8);
#pragma unroll
        for (int nf = 0; nf < 16; ++nf) {
            s16x8 b = *(const s16x8*)(W + (size_t)(nf * 16 + i) * 256 + k0 + G * 8);
            acc[nf] = MFMA_BF16(a, b, acc[nf]);
        }
    }
#pragma unroll
    for (int nf = 0; nf < 16; ++nf) {
        int col = nf * 16 + i;
        float bv = bias[col];
        int h = col >> 5, dh = col & 31;
#pragma unroll
        for (int r = 0; r < 4; ++r) {
            int m = m0 + G * 4 + r;
            int bb = m >> 12, n = m & 4095;
            float v = (acc[nf][r] + bv) * scale;
            Y[(size_t)(((bb << 3) + h) * 4096 + n) * 32 + dh] = f2bf(v);
        }
    }
}

// ---- transposed projection: Vt[b,h,dh,n] = (K @ Wv^T + bv)^T ----
__global__ __launch_bounds__(256) void k_proj_tr(const unsigned short* __restrict__ Kb,
                                                 const unsigned short* __restrict__ W,
                                                 const float* __restrict__ bias,
                                                 unsigned short* __restrict__ Vt) {
    const int wv = threadIdx.x >> 6, lid = threadIdx.x & 63;
    const int i = lid & 15, G = lid >> 4;
    const int n0 = blockIdx.x * 64;
    const int dv0 = blockIdx.y * 64 + wv * 16;
    f32x4 acc[4];
#pragma unroll
    for (int nf = 0; nf < 4; ++nf) acc[nf] = f32x4{0.f, 0.f, 0.f, 0.f};
    const unsigned short* Wrow = W + (size_t)(dv0 + i) * 256;
#pragma unroll
    for (int k0 = 0; k0 < 256; k0 += 32) {
        s16x8 a = *(const s16x8*)(Wrow + k0 + G * 8);
#pragma unroll
        for (int nf = 0; nf < 4; ++nf) {
            s16x8 b = *(const s16x8*)(Kb + (size_t)(n0 + nf * 16 + i) * 256 + k0 + G * 8);
            acc[nf] = MFMA_BF16(a, b, acc[nf]);
        }
    }
#pragma unroll
    for (int r = 0; r < 4; ++r) {
        int dv = dv0 + G * 4 + r;
        float bv = bias[dv];
        int h = dv >> 5, dh = dv & 31;
#pragma unroll
        for (int nf = 0; nf < 4; ++nf) {
            int n = n0 + nf * 16 + i;
            int bb = n >> 12, nn = n & 4095;
            Vt[(size_t)(((bb << 3) + h) * 32 + dh) * 4096 + nn] = f2bf(acc[nf][r] + bv);
        }
    }
}

// ---- flash attention, 32x32 MFMA, register-resident softmax ----
// Grid: 512 blocks = 16 (b,h) x 32 q-blocks of 128 rows; 4 waves x 32 q-rows.
// Qp/Kp [16][4096][32] bf16 (Qp pre-scaled by log2(e)/sqrt(32)), Vt [16][32][4096]
__global__ __launch_bounds__(256) void k_attn(const unsigned short* __restrict__ Qp,
                                              const unsigned short* __restrict__ Kp,
                                              const unsigned short* __restrict__ Vt,
                                              unsigned short* __restrict__ Oa) {
    __shared__ float lred[4][32];
    const int wv = threadIdx.x >> 6, l = threadIdx.x & 63;
    const int ql = l & 31, hi = l >> 5;
    int bid = blockIdx.x;
    int wg = ((bid & 7) << 6) | (bid >> 3);  // XCD swizzle, 512 % 8 == 0, bijective
    int bh = wg >> 5, qblk = wg & 31;
    const unsigned short* Qh = Qp + (size_t)bh * 4096 * 32;
    const unsigned short* Kh = Kp + (size_t)bh * 4096 * 32;
    const unsigned short* Vh = Vt + (size_t)bh * 32 * 4096;
    const int q0 = qblk * 128 + wv * 32;

    // Q B-frags (col=q(=l&31), k=dh half: hi*8+e)
    s16x8 qb0 = *(const s16x8*)(Qh + (size_t)(q0 + ql) * 32 + hi * 8);
    s16x8 qb1 = *(const s16x8*)(Qh + (size_t)(q0 + ql) * 32 + 16 + hi * 8);

    f32x16 acc, Z;
#pragma unroll
    for (int r = 0; r < 16; ++r) { acc[r] = 0.f; Z[r] = 0.f; }
    float mrun = 0.f, lrun = 0.f;

    const unsigned short* Kl = Kh + (size_t)ql * 32 + hi * 8;
    const unsigned short* Vl = Vh + (size_t)ql * 4096 + hi * 8;
    s16x8 ka0 = *(const s16x8*)(Kl);
    s16x8 ka1 = *(const s16x8*)(Kl + 16);
    s16x8 vb0 = *(const s16x8*)(Vl);
    s16x8 vb1 = *(const s16x8*)(Vl + 16);

    for (int t = 0; t < 128; ++t) {
        s16x8 k0 = ka0, k1 = ka1, v0 = vb0, v1 = vb1;
        if (t < 127) {  // prefetch next tile (uniform branch)
            const int j1 = (t + 1) * 32;
            ka0 = *(const s16x8*)(Kl + (size_t)j1 * 32);
            ka1 = *(const s16x8*)(Kl + (size_t)j1 * 32 + 16);
            vb0 = *(const s16x8*)(Vl + j1);
            vb1 = *(const s16x8*)(Vl + j1 + 16);
        }
        // S^T tile: C[row=j_local][col=q=l&31]; lane holds 16 j for its q
        f32x16 st = MFMA32(k0, qb0, Z);
        st = MFMA32(k1, qb1, st);

        float pmax = st[0];
#pragma unroll
        for (int r = 1; r < 16; ++r) pmax = fmaxf(pmax, st[r]);
        pmax = fmaxf(pmax, __shfl_xor(pmax, 32));

        if (__builtin_expect(!__all(pmax <= mrun + 8.f), 0)) {
            // rare rescale path (never fires for bounded scores)
            float mnew = fmaxf(mrun, pmax);
            float corr = __builtin_amdgcn_exp2f(mrun - mnew);
            mrun = mnew;
            lrun *= corr;
            if (hi == 0) lred[wv][ql] = corr;
#pragma unroll
            for (int r = 0; r < 16; ++r)
                acc[r] *= lred[wv][(r & 3) + 8 * (r >> 2) + 4 * hi];
        }

        float rsum = 0.f;
#pragma unroll
        for (int r = 0; r < 16; ++r) {
            float p = __builtin_amdgcn_exp2f(st[r] - mrun);
            st[r] = p;
            rsum += p;
        }
        lrun += rsum + __shfl_xor(rsum, 32);

        // P -> bf16 A-frags fully in-register: 8 cvt_pk + 4 permlane32_swap
        unsigned w00 = cvtpk(st[0], st[1]),   w01 = cvtpk(st[2], st[3]);
        unsigned w10 = cvtpk(st[4], st[5]),   w11 = cvtpk(st[6], st[7]);
        unsigned w20 = cvtpk(st[8], st[9]),   w21 = cvtpk(st[10], st[11]);
        unsigned w30 = cvtpk(st[12], st[13]), w31 = cvtpk(st[14], st[15]);
        u32x2 sA0 = __builtin_amdgcn_permlane32_swap(w00, w10, false, false);
        u32x2 sB0 = __builtin_amdgcn_permlane32_swap(w01, w11, false, false);
        u32x2 sA1 = __builtin_amdgcn_permlane32_swap(w20, w30, false, false);
        u32x2 sB1 = __builtin_amdgcn_permlane32_swap(w21, w31, false, false);
        s16x8 pa0 = mk8(sA0[0], sB0[0], sA0[1], sB0[1]);  // j half 0 (j0..j0+15)
        s16x8 pa1 = mk8(sA1[0], sB1[0], sA1[1], sB1[1]);  // j half 1

        acc = MFMA32(pa0, v0, acc);
        acc = MFMA32(pa1, v1, acc);
    }

    // normalize: redistribute 1/lrun (per q, lives in lane q) via tiny LDS
    float linv = 1.f / lrun;
    if (hi == 0) lred[wv][ql] = linv;
    __syncthreads();
    const int bb = bh >> 3, h = bh & 7;
#pragma unroll
    for (int r = 0; r < 16; ++r) {
        int qr = (r & 3) + 8 * (r >> 2) + 4 * hi;
        float o = acc[r] * lred[wv][qr];
        Oa[(size_t)((bb << 12) + q0 + qr) * 256 + h * 32 + ql] = f2bf(o);
    }
}

// ---- epilogue: out = LN1( LN0(Oa@Wo^T + bo) + relu(LN0(...)) ), fp32 out ----
__global__ __launch_bounds__(256) void k_epi(const unsigned short* __restrict__ Oa,
                                             const unsigned short* __restrict__ W,
                                             const float* __restrict__ bo,
                                             const float* __restrict__ g0,
                                             const float* __restrict__ be0,
                                             const float* __restrict__ g1,
                                             const float* __restrict__ be1,
                                             float* __restrict__ out) {
    const int wv = threadIdx.x >> 6, lid = threadIdx.x & 63;
    const int i = lid & 15, G = lid >> 4;
    const int m0 = blockIdx.x * 64 + wv * 16;
    f32x4 acc[16];
#pragma unroll
    for (int nf = 0; nf < 16; ++nf) acc[nf] = f32x4{0.f, 0.f, 0.f, 0.f};
    const unsigned short* Arow = Oa + (size_t)(m0 + i) * 256;
#pragma unroll
    for (int k0 = 0; k0 < 256; k0 += 32) {
        s16x8 a = *(const s16x8*)(Arow + k0 + G * 8);
#pragma unroll
        for (int nf = 0; nf < 16; ++nf) {
            s16x8 b = *(const s16x8*)(W + (size_t)(nf * 16 + i) * 256 + k0 + G * 8);
            acc[nf] = MFMA_BF16(a, b, acc[nf]);
        }
    }
    f32x4 s1 = f32x4{0.f, 0.f, 0.f, 0.f}, s2 = f32x4{0.f, 0.f, 0.f, 0.f};
#pragma unroll
    for (int nf = 0; nf < 16; ++nf) {
        float bb = bo[nf * 16 + i];
#pragma unroll
        for (int r = 0; r < 4; ++r) {
            float x = acc[nf][r] + bb;
            acc[nf][r] = x;
            s1[r] += x;
            s2[r] += x * x;
        }
    }
#pragma unroll
    for (int mk = 1; mk < 16; mk <<= 1) {
#pragma unroll
        for (int r = 0; r < 4; ++r) {
            s1[r] += __shfl_xor(s1[r], mk);
            s2[r] += __shfl_xor(s2[r], mk);
        }
    }
    f32x4 mu, rs;
#pragma unroll
    for (int r = 0; r < 4; ++r) {
        mu[r] = s1[r] * (1.f / 256.f);
        float var = s2[r] * (1.f / 256.f) - mu[r] * mu[r];
        rs[r] = rsqrtf(var + 1e-5f);
    }
    f32x4 t1 = f32x4{0.f, 0.f, 0.f, 0.f}, t2 = f32x4{0.f, 0.f, 0.f, 0.f};
#pragma unroll
    for (int nf = 0; nf < 16; ++nf) {
        float gv = g0[nf * 16 + i], bv = be0[nf * 16 + i];
#pragma unroll
        for (int r = 0; r < 4; ++r) {
            float y = (acc[nf][r] - mu[r]) * rs[r] * gv + bv;
            float z = y + fmaxf(y, 0.f);
            acc[nf][r] = z;
            t1[r] += z;
            t2[r] += z * z;
        }
    }
#pragma unroll
    for (int mk = 1; mk < 16; mk <<= 1) {
#pragma unroll
        for (int r = 0; r < 4; ++r) {
            t1[r] += __shfl_xor(t1[r], mk);
            t2[r] += __shfl_xor(t2[r], mk);
        }
    }
    f32x4 mu2, rs2;
#pragma unroll
    for (int r = 0; r < 4; ++r) {
        mu2[r] = t1[r] * (1.f / 256.f);
        float var = t2[r] * (1.f / 256.f) - mu2[r] * mu2[r];
        rs2[r] = rsqrtf(var + 1e-5f);
    }
#pragma unroll
    for (int nf = 0; nf < 16; ++nf) {
        int col = nf * 16 + i;
        float gv = g1[col], bv = be1[col];
#pragma unroll
        for (int r = 0; r < 4; ++r) {
            out[(size_t)(m0 + G * 4 + r) * 256 + col] = (acc[nf][r] - mu2[r]) * rs2[r] * gv + bv;
        }
    }
}

extern "C" void kernel_launch(void* const* d_in, const int* in_sizes, int n_in,
                              void* d_out, int out_size, void* d_ws, size_t ws_size,
                              hipStream_t stream) {
    const float* Q   = (const float*)d_in[0];
    const float* K   = (const float*)d_in[1];
    const float* Wq  = (const float*)d_in[2];
    const float* bq  = (const float*)d_in[3];
    const float* Wk  = (const float*)d_in[4];
    const float* bk  = (const float*)d_in[5];
    const float* Wv  = (const float*)d_in[6];
    const float* bv  = (const float*)d_in[7];
    const float* Wo  = (const float*)d_in[8];
    const float* bo  = (const float*)d_in[9];
    const float* g0  = (const float*)d_in[10];
    const float* be0 = (const float*)d_in[11];
    const float* g1  = (const float*)d_in[12];
    const float* be1 = (const float*)d_in[13];
    float* out = (float*)d_out;

    char* ws = (char*)d_ws;
    unsigned short* Wqb = (unsigned short*)(ws + (size_t)0);
    unsigned short* Wkb = (unsigned short*)(ws + ((size_t)128 << 10));
    unsigned short* Wvb = (unsigned short*)(ws + ((size_t)256 << 10));
    unsigned short* Wob = (unsigned short*)(ws + ((size_t)384 << 10));
    size_t off = (size_t)512 << 10;
    const size_t big = (size_t)8192 * 256 * 2;  // 4 MB each
    unsigned short* Qb = (unsigned short*)(ws + off); off += big;
    unsigned short* Kb = (unsigned short*)(ws + off); off += big;
    unsigned short* Qp = (unsigned short*)(ws + off); off += big;
    unsigned short* Kp = (unsigned short*)(ws + off); off += big;
    unsigned short* Vt = (unsigned short*)(ws + off); off += big;
    unsigned short* Oa = (unsigned short*)(ws + off); off += big;

    k_cvt<<<2048, 256, 0, stream>>>(Q, Qb, 524288);
    k_cvt<<<2048, 256, 0, stream>>>(K, Kb, 524288);
    k_cvt<<<64, 256, 0, stream>>>(Wq, Wqb, 16384);
    k_cvt<<<64, 256, 0, stream>>>(Wk, Wkb, 16384);
    k_cvt<<<64, 256, 0, stream>>>(Wv, Wvb, 16384);
    k_cvt<<<64, 256, 0, stream>>>(Wo, Wob, 16384);

    const float qscale = 1.4426950408889634f / sqrtf(32.0f);
    k_proj_rm<<<128, 256, 0, stream>>>(Qb, Wqb, bq, Qp, qscale);
    k_proj_rm<<<128, 256, 0, stream>>>(Kb, Wkb, bk, Kp, 1.0f);
    k_proj_tr<<<dim3(128, 4), 256, 0, stream>>>(Kb, Wvb, bv, Vt);

    k_attn<<<512, 256, 0, stream>>>(Qp, Kp, Vt, Oa);

    k_epi<<<128, 256, 0, stream>>>(Oa, Wob, bo, g0, be0, g1, be1, out);
}

// Round 5
// 149.739 us; speedup vs baseline: 1.9093x; 1.3384x over previous
//
#include <hip/hip_runtime.h>
#include <hip/hip_bf16.h>
#include <math.h>

// ---------------------------------------------------------------------------
// MAB block: Qp=Q@Wq.T+bq, Kp=K@Wk.T+bk, Vp=K@Wv.T+bv (8 heads, dh=32)
// attn = softmax(Qp Kp^T / sqrt(32)) @ Vp ; out = attn@Wo.T+bo ; LN0 ;
// out = LN1(out + relu(out)).
// Attention: 32x32x16 MFMA, swapped QK^T (lane-local softmax), software-
// pipelined QK (1 tile ahead), -mrun folded into MFMA C-operand, row-sums
// accumulated via MFMA with ones-fragment (no per-iter shuffles/LDS).
// ---------------------------------------------------------------------------

typedef __attribute__((ext_vector_type(4))) float f32x4;
typedef __attribute__((ext_vector_type(16))) float f32x16;
typedef __attribute__((ext_vector_type(8))) short s16x8;
typedef __attribute__((ext_vector_type(2))) unsigned u32x2;

#define MFMA_BF16(A, B, C) __builtin_amdgcn_mfma_f32_16x16x32_bf16((A), (B), (C), 0, 0, 0)
#define MFMA32(A, B, C) __builtin_amdgcn_mfma_f32_32x32x16_bf16((A), (B), (C), 0, 0, 0)

static __device__ __forceinline__ unsigned short f2bf(float f) {
    union { float f; unsigned u; } v; v.f = f;
    unsigned u = v.u;
    unsigned r = (u + 0x7FFFu + ((u >> 16) & 1u)) >> 16;  // RNE
    return (unsigned short)r;
}

static __device__ __forceinline__ unsigned cvtpk(float lo, float hi) {
    unsigned r;
    asm("v_cvt_pk_bf16_f32 %0, %1, %2" : "=v"(r) : "v"(lo), "v"(hi));
    return r;
}

static __device__ __forceinline__ s16x8 mk8(unsigned a, unsigned b, unsigned c, unsigned d) {
    union { unsigned u[4]; s16x8 v; } x;
    x.u[0] = a; x.u[1] = b; x.u[2] = c; x.u[3] = d;
    return x.v;
}

// ---- merged fp32 -> bf16 convert: Q, K, and the 4 weight matrices ----
__global__ __launch_bounds__(256) void k_cvt_all(
    const float* __restrict__ Q, const float* __restrict__ K,
    const float* __restrict__ Wq, const float* __restrict__ Wk,
    const float* __restrict__ Wv, const float* __restrict__ Wo,
    unsigned short* __restrict__ Qb, unsigned short* __restrict__ Kb,
    unsigned short* __restrict__ Wqb, unsigned short* __restrict__ Wkb,
    unsigned short* __restrict__ Wvb, unsigned short* __restrict__ Wob) {
    int bid = blockIdx.x, tid = threadIdx.x;
    const float* src;
    unsigned short* dst;
    int idx;
    if (bid < 2048) {
        src = Q; dst = Qb; idx = bid * 256 + tid;
    } else if (bid < 4096) {
        src = K; dst = Kb; idx = (bid - 2048) * 256 + tid;
    } else {
        int w = (bid - 4096) >> 6;
        src = (w == 0) ? Wq : (w == 1) ? Wk : (w == 2) ? Wv : Wo;
        dst = (w == 0) ? Wqb : (w == 1) ? Wkb : (w == 2) ? Wvb : Wob;
        idx = ((bid - 4096) & 63) * 256 + tid;
    }
    float4 v = ((const float4*)src)[idx];
    ushort4 o;
    o.x = f2bf(v.x); o.y = f2bf(v.y); o.z = f2bf(v.z); o.w = f2bf(v.w);
    ((ushort4*)dst)[idx] = o;
}

// ---- merged projections: Q-proj(rm) + K-proj(rm) + V-proj(transposed) ----
// 128 threads (2 waves). bid<256: Qp; bid<512: Kp; bid in [512,1536): Vt.
__global__ __launch_bounds__(128) void k_proj(
    const unsigned short* __restrict__ Qb, const unsigned short* __restrict__ Kb,
    const unsigned short* __restrict__ Wqb, const unsigned short* __restrict__ Wkb,
    const unsigned short* __restrict__ Wvb,
    const float* __restrict__ bq, const float* __restrict__ bk, const float* __restrict__ bv,
    unsigned short* __restrict__ Qp, unsigned short* __restrict__ Kp,
    unsigned short* __restrict__ Vtp, float qscale) {
    const int wv = threadIdx.x >> 6, lid = threadIdx.x & 63;
    const int i = lid & 15, G = lid >> 4;
    const int bid = blockIdx.x;
    if (bid < 512) {
        const int which = bid >> 8;
        const unsigned short* X = which ? Kb : Qb;
        const unsigned short* W = which ? Wkb : Wqb;
        const float* bias = which ? bk : bq;
        unsigned short* Y = which ? Kp : Qp;
        const float scale = which ? 1.0f : qscale;
        const int m0 = (bid & 255) * 32 + wv * 16;
        f32x4 acc[16];
#pragma unroll
        for (int nf = 0; nf < 16; ++nf) acc[nf] = f32x4{0.f, 0.f, 0.f, 0.f};
        const unsigned short* Xrow = X + (size_t)(m0 + i) * 256;
#pragma unroll
        for (int k0 = 0; k0 < 256; k0 += 32) {
            s16x8 a = *(const s16x8*)(Xrow + k0 + G * 8);
#pragma unroll
            for (int nf = 0; nf < 16; ++nf) {
                s16x8 b = *(const s16x8*)(W + (size_t)(nf * 16 + i) * 256 + k0 + G * 8);
                acc[nf] = MFMA_BF16(a, b, acc[nf]);
            }
        }
#pragma unroll
        for (int nf = 0; nf < 16; ++nf) {
            int col = nf * 16 + i;
            float bvv = bias[col];
            int h = col >> 5, dh = col & 31;
#pragma unroll
            for (int r = 0; r < 4; ++r) {
                int m = m0 + G * 4 + r;
                int bb = m >> 12, n = m & 4095;
                float v = (acc[nf][r] + bvv) * scale;
                Y[(size_t)(((bb << 3) + h) * 4096 + n) * 32 + dh] = f2bf(v);
            }
        }
    } else {
        const int tid = bid - 512;                  // [0, 1024)
        const int n0 = (tid & 127) * 64;            // 128 tiles x 64 = 8192 rows
        const int dv0 = (tid >> 7) * 32 + wv * 16;  // 8 tiles x 32 = 256 dv
        f32x4 acc[4];
#pragma unroll
        for (int nf = 0; nf < 4; ++nf) acc[nf] = f32x4{0.f, 0.f, 0.f, 0.f};
        const unsigned short* Wrow = Wvb + (size_t)(dv0 + i) * 256;
#pragma unroll
        for (int k0 = 0; k0 < 256; k0 += 32) {
            s16x8 a = *(const s16x8*)(Wrow + k0 + G * 8);
#pragma unroll
            for (int nf = 0; nf < 4; ++nf) {
                s16x8 b = *(const s16x8*)(Kb + (size_t)(n0 + nf * 16 + i) * 256 + k0 + G * 8);
                acc[nf] = MFMA_BF16(a, b, acc[nf]);
            }
        }
#pragma unroll
        for (int r = 0; r < 4; ++r) {
            int dv = dv0 + G * 4 + r;
            float bvv = bv[dv];
            int h = dv >> 5, dh = dv & 31;
#pragma unroll
            for (int nf = 0; nf < 4; ++nf) {
                int n = n0 + nf * 16 + i;
                int bb = n >> 12, nn = n & 4095;
                Vtp[(size_t)(((bb << 3) + h) * 32 + dh) * 4096 + nn] = f2bf(acc[nf][r] + bvv);
            }
        }
    }
}

// ---- softmax + PV body for one 32-wide KV tile (register-resident) ----
static __device__ __forceinline__ void softmax_pv(
    f32x16& st, f32x16& stn, f32x16& acc, f32x16& accL, f32x16& Cin,
    const s16x8 v0, const s16x8 v1, const s16x8 ones,
    float lred[][32], int wv, int ql, int hi) {
    // tile max (per-lane over 16 regs; __all covers all 64 lanes)
    float a0 = fmaxf(st[0], st[1]),   a1 = fmaxf(st[2], st[3]);
    float a2 = fmaxf(st[4], st[5]),   a3 = fmaxf(st[6], st[7]);
    float a4 = fmaxf(st[8], st[9]),   a5 = fmaxf(st[10], st[11]);
    float a6 = fmaxf(st[12], st[13]), a7 = fmaxf(st[14], st[15]);
    float b0 = fmaxf(fmaxf(a0, a1), fmaxf(a2, a3));
    float b1 = fmaxf(fmaxf(a4, a5), fmaxf(a6, a7));
    float pmax = fmaxf(b0, b1);
    if (__builtin_expect(!__all(pmax <= 8.f), 0)) {
        // rare rescale: dm = max(per-q max, 0); shift running-max by dm
        float pm = fmaxf(pmax, __shfl_xor(pmax, 32));
        float dm = fmaxf(pm, 0.f);
        float corr = __builtin_amdgcn_exp2f(-dm);
        if (hi == 0) lred[wv][ql] = corr;
#pragma unroll
        for (int r = 0; r < 16; ++r) { st[r] -= dm; stn[r] -= dm; Cin[r] -= dm; }
#pragma unroll
        for (int r = 0; r < 16; ++r) {
            float c = lred[wv][(r & 3) + 8 * (r >> 2) + 4 * hi];
            acc[r] *= c; accL[r] *= c;
        }
    }
#pragma unroll
    for (int r = 0; r < 16; ++r) st[r] = __builtin_amdgcn_exp2f(st[r]);
    unsigned w00 = cvtpk(st[0], st[1]),   w01 = cvtpk(st[2], st[3]);
    unsigned w10 = cvtpk(st[4], st[5]),   w11 = cvtpk(st[6], st[7]);
    unsigned w20 = cvtpk(st[8], st[9]),   w21 = cvtpk(st[10], st[11]);
    unsigned w30 = cvtpk(st[12], st[13]), w31 = cvtpk(st[14], st[15]);
    u32x2 sA0 = __builtin_amdgcn_permlane32_swap(w00, w10, false, false);
    u32x2 sB0 = __builtin_amdgcn_permlane32_swap(w01, w11, false, false);
    u32x2 sA1 = __builtin_amdgcn_permlane32_swap(w20, w30, false, false);
    u32x2 sB1 = __builtin_amdgcn_permlane32_swap(w21, w31, false, false);
    s16x8 pa0 = mk8(sA0[0], sB0[0], sA0[1], sB0[1]);  // P, j half 0
    s16x8 pa1 = mk8(sA1[0], sB1[0], sA1[1], sB1[1]);  // P, j half 1
    acc  = MFMA32(pa0, v0, acc);
    acc  = MFMA32(pa1, v1, acc);
    accL = MFMA32(pa0, ones, accL);  // row-sums ride the MFMA pipe
    accL = MFMA32(pa1, ones, accL);
}

// ---- flash attention, pipelined: QK(t+1) issued before softmax(t) ----
// Grid: 512 blocks = 16 (b,h) x 32 q-blocks of 128 rows; 4 waves x 32 q-rows.
__global__ __launch_bounds__(256) void k_attn(const unsigned short* __restrict__ Qp,
                                              const unsigned short* __restrict__ Kp,
                                              const unsigned short* __restrict__ Vt,
                                              unsigned short* __restrict__ Oa) {
    __shared__ float lred[4][32];
    const int wv = threadIdx.x >> 6, l = threadIdx.x & 63;
    const int ql = l & 31, hi = l >> 5;
    int bid = blockIdx.x;
    int wg = ((bid & 7) << 6) | (bid >> 3);  // XCD swizzle, 512 % 8 == 0, bijective
    int bh = wg >> 5, qblk = wg & 31;
    const unsigned short* Qh = Qp + (size_t)bh * 4096 * 32;
    const unsigned short* Kh = Kp + (size_t)bh * 4096 * 32;
    const unsigned short* Vh = Vt + (size_t)bh * 32 * 4096;
    const int q0 = qblk * 128 + wv * 32;

    s16x8 qb0 = *(const s16x8*)(Qh + (size_t)(q0 + ql) * 32 + hi * 8);
    s16x8 qb1 = *(const s16x8*)(Qh + (size_t)(q0 + ql) * 32 + 16 + hi * 8);

    f32x16 acc, accL, Cin;
#pragma unroll
    for (int r = 0; r < 16; ++r) { acc[r] = 0.f; accL[r] = 0.f; Cin[r] = 0.f; }
    const s16x8 ONES = mk8(0x3F803F80u, 0x3F803F80u, 0x3F803F80u, 0x3F803F80u);

    const unsigned short* Kl = Kh + (size_t)ql * 32 + hi * 8;
    const unsigned short* Vl = Vh + (size_t)ql * 4096 + hi * 8;
    // K tile stride 1024 elems (32 rows x 32), V tile stride 32 elems
    s16x8 kA0 = *(const s16x8*)(Kl + 0),    kA1 = *(const s16x8*)(Kl + 16);
    s16x8 kB0 = *(const s16x8*)(Kl + 1024), kB1 = *(const s16x8*)(Kl + 1040);
    s16x8 vA0 = *(const s16x8*)(Vl + 0),    vA1 = *(const s16x8*)(Vl + 16);
    s16x8 vB0 = *(const s16x8*)(Vl + 32),   vB1 = *(const s16x8*)(Vl + 48);

    f32x16 st = MFMA32(kA0, qb0, Cin);  // tile 0
    st = MFMA32(kA1, qb1, st);
    f32x16 stn;

    for (int t = 0; t < 128; t += 2) {
        {   // body: tile t (K/V in A bufs); tile t+1 K in B bufs
            int t2 = (t + 2 < 128) ? t + 2 : 126;
            kA0 = *(const s16x8*)(Kl + (size_t)t2 * 1024);
            kA1 = *(const s16x8*)(Kl + (size_t)t2 * 1024 + 16);
            stn = MFMA32(kB0, qb0, Cin);   // QK for tile t+1, ahead of softmax(t)
            stn = MFMA32(kB1, qb1, stn);
            softmax_pv(st, stn, acc, accL, Cin, vA0, vA1, ONES, lred, wv, ql, hi);
            vA0 = *(const s16x8*)(Vl + t2 * 32);
            vA1 = *(const s16x8*)(Vl + t2 * 32 + 16);
            st = stn;
        }
        {   // body: tile t+1 (K/V in B bufs)
            int t2 = (t + 3 < 128) ? t + 3 : 126;
            kB0 = *(const s16x8*)(Kl + (size_t)t2 * 1024);
            kB1 = *(const s16x8*)(Kl + (size_t)t2 * 1024 + 16);
            stn = MFMA32(kA0, qb0, Cin);   // QK for tile t+2 (garbage on last pair; unused)
            stn = MFMA32(kA1, qb1, stn);
            softmax_pv(st, stn, acc, accL, Cin, vB0, vB1, ONES, lred, wv, ql, hi);
            vB0 = *(const s16x8*)(Vl + t2 * 32);
            vB1 = *(const s16x8*)(Vl + t2 * 32 + 16);
            st = stn;
        }
    }

    // normalize: accL[r] holds the row-sum for exactly acc[r]'s q-row
    const int bb = bh >> 3, h = bh & 7;
#pragma unroll
    for (int r = 0; r < 16; ++r) {
        int qr = (r & 3) + 8 * (r >> 2) + 4 * hi;
        float o = acc[r] / accL[r];
        Oa[(size_t)((bb << 12) + q0 + qr) * 256 + h * 32 + ql] = f2bf(o);
    }
}

// ---- epilogue: out = LN1( LN0(Oa@Wo^T + bo) + relu(LN0(...)) ), fp32 out ----
// 128 threads (2 waves), grid 256 -> all CUs
__global__ __launch_bounds__(128) void k_epi(const unsigned short* __restrict__ Oa,
                                             const unsigned short* __restrict__ W,
                                             const float* __restrict__ bo,
                                             const float* __restrict__ g0,
                                             const float* __restrict__ be0,
                                             const float* __restrict__ g1,
                                             const float* __restrict__ be1,
                                             float* __restrict__ out) {
    const int wv = threadIdx.x >> 6, lid = threadIdx.x & 63;
    const int i = lid & 15, G = lid >> 4;
    const int m0 = blockIdx.x * 32 + wv * 16;
    f32x4 acc[16];
#pragma unroll
    for (int nf = 0; nf < 16; ++nf) acc[nf] = f32x4{0.f, 0.f, 0.f, 0.f};
    const unsigned short* Arow = Oa + (size_t)(m0 + i) * 256;
#pragma unroll
    for (int k0 = 0; k0 < 256; k0 += 32) {
        s16x8 a = *(const s16x8*)(Arow + k0 + G * 8);
#pragma unroll
        for (int nf = 0; nf < 16; ++nf) {
            s16x8 b = *(const s16x8*)(W + (size_t)(nf * 16 + i) * 256 + k0 + G * 8);
            acc[nf] = MFMA_BF16(a, b, acc[nf]);
        }
    }
    f32x4 s1 = f32x4{0.f, 0.f, 0.f, 0.f}, s2 = f32x4{0.f, 0.f, 0.f, 0.f};
#pragma unroll
    for (int nf = 0; nf < 16; ++nf) {
        float bb = bo[nf * 16 + i];
#pragma unroll
        for (int r = 0; r < 4; ++r) {
            float x = acc[nf][r] + bb;
            acc[nf][r] = x;
            s1[r] += x;
            s2[r] += x * x;
        }
    }
#pragma unroll
    for (int mk = 1; mk < 16; mk <<= 1) {
#pragma unroll
        for (int r = 0; r < 4; ++r) {
            s1[r] += __shfl_xor(s1[r], mk);
            s2[r] += __shfl_xor(s2[r], mk);
        }
    }
    f32x4 mu, rs;
#pragma unroll
    for (int r = 0; r < 4; ++r) {
        mu[r] = s1[r] * (1.f / 256.f);
        float var = s2[r] * (1.f / 256.f) - mu[r] * mu[r];
        rs[r] = rsqrtf(var + 1e-5f);
    }
    f32x4 t1 = f32x4{0.f, 0.f, 0.f, 0.f}, t2 = f32x4{0.f, 0.f, 0.f, 0.f};
#pragma unroll
    for (int nf = 0; nf < 16; ++nf) {
        float gv = g0[nf * 16 + i], bv = be0[nf * 16 + i];
#pragma unroll
        for (int r = 0; r < 4; ++r) {
            float y = (acc[nf][r] - mu[r]) * rs[r] * gv + bv;
            float z = y + fmaxf(y, 0.f);
            acc[nf][r] = z;
            t1[r] += z;
            t2[r] += z * z;
        }
    }
#pragma unroll
    for (int mk = 1; mk < 16; mk <<= 1) {
#pragma unroll
        for (int r = 0; r < 4; ++r) {
            t1[r] += __shfl_xor(t1[r], mk);
            t2[r] += __shfl_xor(t2[r], mk);
        }
    }
    f32x4 mu2, rs2;
#pragma unroll
    for (int r = 0; r < 4; ++r) {
        mu2[r] = t1[r] * (1.f / 256.f);
        float var = t2[r] * (1.f / 256.f) - mu2[r] * mu2[r];
        rs2[r] = rsqrtf(var + 1e-5f);
    }
#pragma unroll
    for (int nf = 0; nf < 16; ++nf) {
        int col = nf * 16 + i;
        float gv = g1[col], bv = be1[col];
#pragma unroll
        for (int r = 0; r < 4; ++r) {
            out[(size_t)(m0 + G * 4 + r) * 256 + col] = (acc[nf][r] - mu2[r]) * rs2[r] * gv + bv;
        }
    }
}

extern "C" void kernel_launch(void* const* d_in, const int* in_sizes, int n_in,
                              void* d_out, int out_size, void* d_ws, size_t ws_size,
                              hipStream_t stream) {
    const float* Q   = (const float*)d_in[0];
    const float* K   = (const float*)d_in[1];
    const float* Wq  = (const float*)d_in[2];
    const float* bq  = (const float*)d_in[3];
    const float* Wk  = (const float*)d_in[4];
    const float* bk  = (const float*)d_in[5];
    const float* Wv  = (const float*)d_in[6];
    const float* bv  = (const float*)d_in[7];
    const float* Wo  = (const float*)d_in[8];
    const float* bo  = (const float*)d_in[9];
    const float* g0  = (const float*)d_in[10];
    const float* be0 = (const float*)d_in[11];
    const float* g1  = (const float*)d_in[12];
    const float* be1 = (const float*)d_in[13];
    float* out = (float*)d_out;

    char* ws = (char*)d_ws;
    unsigned short* Wqb = (unsigned short*)(ws + (size_t)0);
    unsigned short* Wkb = (unsigned short*)(ws + ((size_t)128 << 10));
    unsigned short* Wvb = (unsigned short*)(ws + ((size_t)256 << 10));
    unsigned short* Wob = (unsigned short*)(ws + ((size_t)384 << 10));
    size_t off = (size_t)512 << 10;
    const size_t big = (size_t)8192 * 256 * 2;  // 4 MB each
    unsigned short* Qb = (unsigned short*)(ws + off); off += big;
    unsigned short* Kb = (unsigned short*)(ws + off); off += big;
    unsigned short* Qp = (unsigned short*)(ws + off); off += big;
    unsigned short* Kp = (unsigned short*)(ws + off); off += big;
    unsigned short* Vt = (unsigned short*)(ws + off); off += big;
    unsigned short* Oa = (unsigned short*)(ws + off); off += big;

    k_cvt_all<<<4352, 256, 0, stream>>>(Q, K, Wq, Wk, Wv, Wo,
                                        Qb, Kb, Wqb, Wkb, Wvb, Wob);

    const float qscale = 1.4426950408889634f / sqrtf(32.0f);
    k_proj<<<1536, 128, 0, stream>>>(Qb, Kb, Wqb, Wkb, Wvb, bq, bk, bv,
                                     Qp, Kp, Vt, qscale);

    k_attn<<<512, 256, 0, stream>>>(Qp, Kp, Vt, Oa);

    k_epi<<<256, 128, 0, stream>>>(Oa, Wob, bo, g0, be0, g1, be1, out);
}